// Round 12
// baseline (309.280 us; speedup 1.0000x reference)
//
#include <hip/hip_runtime.h>
#include <hip/hip_bf16.h>
#include <hip/hip_fp16.h>
#include <math.h>

#define SLOPE 0.2f

typedef __attribute__((ext_vector_type(8))) short bf16x8;
typedef __attribute__((ext_vector_type(4))) float f32x4;

// bf16 helpers (manual, RNE)
__device__ inline unsigned short f2bf(float f) {
    unsigned u = __float_as_uint(f);
    u += 0x7FFF + ((u >> 16) & 1);
    return (unsigned short)(u >> 16);
}
__device__ inline float bf2f(unsigned short s) {
    return __uint_as_float(((unsigned)s) << 16);
}
// HW packed f32x2 -> bf16x2 (RNE), gfx950. lo = bf16(a), hi = bf16(b).
__device__ inline unsigned cvt_pk_bf16(float a, float b) {
    unsigned r;
    asm("v_cvt_pk_bf16_f32 %0, %1, %2" : "=v"(r) : "v"(a), "v"(b));
    return r;
}

// ---------------- CSR build (separate dispatches; R6: coop grid.sync ~100us
// per barrier on MI355X -> NEVER use cooperative launch for this) ----------

// Fused: cvt_w (blocks 0..255) || deg+rank (remaining blocks).
__global__ void deg_cvtw_kernel(const int* __restrict__ dst, int* __restrict__ deg,
                                int* __restrict__ rank, int E,
                                const float* __restrict__ W1,
                                const float* __restrict__ W2,
                                unsigned short* __restrict__ Wt1,
                                unsigned short* __restrict__ Wt2) {
    if (blockIdx.x < 256) {
        const int k = blockIdx.x, c = threadIdx.x;
        Wt1[c * 256 + k] = f2bf(W1[k * 256 + c]);
        if (c < 64) Wt2[c * 256 + k] = f2bf(W2[k * 64 + c]);
    } else {
        const int i = (blockIdx.x - 256) * blockDim.x + threadIdx.x;
        if (i < E) rank[i] = atomicAdd(&deg[dst[i]], 1);
    }
}

// Two-level device-wide exclusive scan (N <= 65536 so nb <= 256).
__global__ __launch_bounds__(256) void psum_kernel(const int* __restrict__ deg,
                                                   int* __restrict__ bsum, int n) {
    const int t = threadIdx.x;
    const int i = blockIdx.x * 256 + t;
    int v = (i < n) ? deg[i] : 0;
#pragma unroll
    for (int o = 1; o < 64; o <<= 1) v += __shfl_xor(v, o, 64);
    __shared__ int ws[4];
    if ((t & 63) == 0) ws[t >> 6] = v;
    __syncthreads();
    if (t == 0) bsum[blockIdx.x] = ws[0] + ws[1] + ws[2] + ws[3];
}

__global__ __launch_bounds__(256) void scan2_kernel(const int* __restrict__ deg,
                                                    const int* __restrict__ bsum,
                                                    int* __restrict__ offs, int n) {
    const int b = blockIdx.x, t = threadIdx.x;
    const int lane = t & 63, w = t >> 6;

    int contrib = (t < b) ? bsum[t] : 0;
#pragma unroll
    for (int o = 1; o < 64; o <<= 1) contrib += __shfl_xor(contrib, o, 64);
    __shared__ int wsum[4];
    if (lane == 0) wsum[w] = contrib;
    __syncthreads();
    const int base = wsum[0] + wsum[1] + wsum[2] + wsum[3];

    const int i = b * 256 + t;
    const int v = (i < n) ? deg[i] : 0;
    int incl = v;
#pragma unroll
    for (int o = 1; o < 64; o <<= 1) {
        const int u = __shfl_up(incl, o, 64);
        if (lane >= o) incl += u;
    }
    __shared__ int wtot[4];
    if (lane == 63) wtot[w] = incl;
    __syncthreads();
    int wbase = 0;
#pragma unroll
    for (int k = 0; k < 4; ++k)
        if (k < w) wbase += wtot[k];

    const int excl = base + wbase + incl - v;
    if (i < n) offs[i] = excl;
    if (i == n - 1) offs[n] = excl + v;
}

// ---------------- fused fill || layer-1 GEMM -------------------------------
__global__ __launch_bounds__(256) void gemm1_fill(const float* __restrict__ Xf,
                                                  const unsigned short* __restrict__ Wt,
                                                  const float* __restrict__ AL,
                                                  const float* __restrict__ AR,
                                                  unsigned short* __restrict__ Hout,
                                                  float* __restrict__ el,
                                                  float* __restrict__ er, int n, int GB,
                                                  const int* __restrict__ src,
                                                  const int* __restrict__ dst,
                                                  const int* __restrict__ offs,
                                                  const int* __restrict__ rank,
                                                  int* __restrict__ csr_src, int E) {
    constexpr int LDR = 72;
    __shared__ __align__(16) unsigned short Xs[128 * LDR];
    __shared__ __align__(16) unsigned short Ws[256 * LDR];

    if (blockIdx.x >= GB) {
        // ---- fill branch ----
        const int i = (blockIdx.x - GB) * blockDim.x + threadIdx.x;
        if (i < E) csr_src[offs[dst[i]] + rank[i]] = src[i];
        return;
    }

    // ---- gemm1 branch: 128 nodes x ALL 256 outputs, X fetched+cvt ONCE ----
    const int tid = threadIdx.x;
    const int wave = tid >> 6, lane = tid & 63;
    const int col16 = lane & 15, quad = lane >> 4;
    const int node0 = blockIdx.x * 128;

    f32x4 acc[16][2];
#pragma unroll
    for (int ft = 0; ft < 16; ++ft)
#pragma unroll
        for (int nt = 0; nt < 2; ++nt) acc[ft][nt] = (f32x4){0.f, 0.f, 0.f, 0.f};

    const int rr = tid >> 3;
    const int cc = (tid & 7) * 8;

    for (int k0 = 0; k0 < 256; k0 += 64) {
#pragma unroll
        for (int p = 0; p < 4; ++p) {
            const int row = rr + p * 32;
            int gx = node0 + row; if (gx >= n) gx = n - 1;
            const float4* xp = (const float4*)&Xf[(long long)gx * 256 + k0 + cc];
            const float4 a = xp[0];
            const float4 b = xp[1];
            uint4 pk;
            pk.x = cvt_pk_bf16(a.x, a.y);
            pk.y = cvt_pk_bf16(a.z, a.w);
            pk.z = cvt_pk_bf16(b.x, b.y);
            pk.w = cvt_pk_bf16(b.z, b.w);
            *(uint4*)&Xs[row * LDR + cc] = pk;
        }
#pragma unroll
        for (int p = 0; p < 8; ++p) {
            const int row = rr + p * 32;   // 0..255 output features
            *(bf16x8*)&Ws[row * LDR + cc] =
                *(const bf16x8*)&Wt[(long long)row * 256 + k0 + cc];
        }
        __syncthreads();
#pragma unroll
        for (int ks = 0; ks < 64; ks += 32) {
            bf16x8 bfrag[2];
#pragma unroll
            for (int nt = 0; nt < 2; ++nt)
                bfrag[nt] = *(const bf16x8*)&Xs[(wave * 32 + nt * 16 + col16) * LDR +
                                                ks + quad * 8];
#pragma unroll
            for (int ft = 0; ft < 16; ++ft) {
                const bf16x8 afrag =
                    *(const bf16x8*)&Ws[(ft * 16 + col16) * LDR + ks + quad * 8];
                acc[ft][0] = __builtin_amdgcn_mfma_f32_16x16x32_bf16(afrag, bfrag[0],
                                                                     acc[ft][0], 0, 0, 0);
                acc[ft][1] = __builtin_amdgcn_mfma_f32_16x16x32_bf16(afrag, bfrag[1],
                                                                     acc[ft][1], 0, 0, 0);
            }
        }
        __syncthreads();
    }

    float elp[2][4] = {{0.f}, {0.f}};
    float erp[2][4] = {{0.f}, {0.f}};
#pragma unroll
    for (int ft = 0; ft < 16; ++ft) {
        const int hb = ft >> 2;             // head 0..3
        float alw[4], arw[4];
#pragma unroll
        for (int r = 0; r < 4; ++r) {
            const int d = (ft & 3) * 16 + quad * 4 + r;
            alw[r] = AL[hb * 64 + d];
            arw[r] = AR[hb * 64 + d];
        }
#pragma unroll
        for (int nt = 0; nt < 2; ++nt) {
            const int node = node0 + wave * 32 + nt * 16 + col16;
            if (node < n) {
                uint2 pk;
                pk.x = cvt_pk_bf16(acc[ft][nt][0], acc[ft][nt][1]);
                pk.y = cvt_pk_bf16(acc[ft][nt][2], acc[ft][nt][3]);
                *(uint2*)&Hout[(long long)node * 256 + ft * 16 + quad * 4] = pk;
            }
#pragma unroll
            for (int r = 0; r < 4; ++r) {
                elp[nt][hb] = fmaf(acc[ft][nt][r], alw[r], elp[nt][hb]);
                erp[nt][hb] = fmaf(acc[ft][nt][r], arw[r], erp[nt][hb]);
            }
        }
    }
#pragma unroll
    for (int nt = 0; nt < 2; ++nt)
#pragma unroll
        for (int hb = 0; hb < 4; ++hb) {
            elp[nt][hb] += __shfl_xor(elp[nt][hb], 16, 64);
            elp[nt][hb] += __shfl_xor(elp[nt][hb], 32, 64);
            erp[nt][hb] += __shfl_xor(erp[nt][hb], 16, 64);
            erp[nt][hb] += __shfl_xor(erp[nt][hb], 32, 64);
        }
    if (quad == 0) {
#pragma unroll
        for (int nt = 0; nt < 2; ++nt) {
            const int node = node0 + wave * 32 + nt * 16 + col16;
            if (node < n) {
#pragma unroll
                for (int hb = 0; hb < 4; ++hb) {
                    el[node * 4 + hb] = elp[nt][hb];
                    er[node * 4 + hb] = erp[nt][hb];
                }
            }
        }
    }
}

// ---------------- fused aggr1 + layer-2 GEMM --------------------------------
// Block = 512 threads (8 waves), 64 nodes. Phase A: each wave runs the proven
// aggr1 loop for 8 nodes, writing bf16 x2 rows (bias+ELU) into LDS (never
// global). Phase B: gemm2 straight out of LDS. Kills x2's HBM round-trip
// (25.6 MB) + one dispatch.
__global__ __launch_bounds__(512) void aggr1_gemm2(const unsigned short* __restrict__ Hf,
                                                   const float* __restrict__ el,
                                                   const float* __restrict__ er,
                                                   const int* __restrict__ offs,
                                                   const int* __restrict__ csr,
                                                   const float* __restrict__ bias,
                                                   const unsigned short* __restrict__ Wt2,
                                                   const float* __restrict__ AL2,
                                                   const float* __restrict__ AR2,
                                                   unsigned short* __restrict__ Hout,
                                                   float* __restrict__ el2,
                                                   float* __restrict__ er2, int n) {
    constexpr int LDX = 264;   // 256 + 8 pad: stride 132 dwords == 4 mod 32 (2-way ok)
    constexpr int LDR = 72;
    __shared__ __align__(16) unsigned short x2s[64 * LDX];
    __shared__ __align__(16) unsigned short Ws[64 * LDR];
    __shared__ float elq[2][64], erq[2][64];

    const int tid = threadIdx.x;
    const int wave = tid >> 6, lane = tid & 63;
    const int node0 = blockIdx.x * 64;

    // ---- Phase A: aggregation (8 rounds, wave -> one node per round) ----
    {
        const int g = lane >> 4;       // edge subgroup
        const int r = lane & 15;       // feature slot
        const int h = r >> 2;          // head
        for (int rnd = 0; rnd < 8; ++rnd) {
            const int ln = rnd * 8 + wave;
            const int node = node0 + ln;
            if (node < n) {
                const int beg = offs[node], end = offs[node + 1];
                const float erv = er[node * 4 + h];
                float acc[16];
#pragma unroll
                for (int q = 0; q < 16; ++q) acc[q] = 0.f;
                float l = 0.f;
                const int nb = (end - beg + 3) >> 2;
                int ci = beg + g; if (ci >= end) ci = end - 1;
                int s = csr[ci];
#pragma unroll 2
                for (int it = 0; it < nb; ++it) {
                    const int ei = beg + it * 4 + g;
                    const bool ok = ei < end;
                    int nci = ei + 4; if (nci >= end) nci = end - 1;
                    const int sn = csr[nci];
                    float e = el[s * 4 + h] + erv;
                    e = (e > 0.f) ? e : SLOPE * e;
                    float p = __expf(fminf(e, 80.f));
                    if (!ok) p = 0.f;
                    const uint4* hp = (const uint4*)(Hf + (s << 8) + (r << 4));
                    const uint4 u0 = hp[0];
                    const uint4 u1 = hp[1];
                    l += p;
                    const unsigned uu[8] = {u0.x, u0.y, u0.z, u0.w, u1.x, u1.y, u1.z, u1.w};
#pragma unroll
                    for (int q = 0; q < 8; ++q) {
                        const float flo = __uint_as_float(uu[q] << 16);
                        const float fhi = __uint_as_float(uu[q] & 0xFFFF0000u);
                        acc[2 * q]     = fmaf(p, flo, acc[2 * q]);
                        acc[2 * q + 1] = fmaf(p, fhi, acc[2 * q + 1]);
                    }
                    s = sn;
                }
#pragma unroll
                for (int q = 0; q < 16; ++q) {
                    acc[q] += __shfl_xor(acc[q], 16, 64);
                    acc[q] += __shfl_xor(acc[q], 32, 64);
                }
                l += __shfl_xor(l, 16, 64);
                l += __shfl_xor(l, 32, 64);
                if (g == 0) {
                    const float inv = (l > 0.f) ? 1.f / l : 0.f;
                    unsigned o[8];
#pragma unroll
                    for (int q = 0; q < 8; ++q) {
                        float v0 = acc[2 * q]     * inv + bias[r * 16 + 2 * q];
                        float v1 = acc[2 * q + 1] * inv + bias[r * 16 + 2 * q + 1];
                        v0 = (v0 > 0.f) ? v0 : expm1f(v0);   // ELU
                        v1 = (v1 > 0.f) ? v1 : expm1f(v1);
                        o[q] = cvt_pk_bf16(v0, v1);
                    }
                    uint4* op = (uint4*)&x2s[ln * LDX + r * 16];
                    op[0] = make_uint4(o[0], o[1], o[2], o[3]);
                    op[1] = make_uint4(o[4], o[5], o[6], o[7]);
                }
            } else if (g == 0) {
                uint4* op = (uint4*)&x2s[ln * LDX + r * 16];
                op[0] = make_uint4(0, 0, 0, 0);
                op[1] = make_uint4(0, 0, 0, 0);
            }
        }
    }
    __syncthreads();

    // ---- Phase B: gemm2 from LDS. wave -> node tile (wave&3), feat pair (wave>>2)
    const int col16 = lane & 15, quad = lane >> 4;
    const int nt = wave & 3;
    const int fp = wave >> 2;

    f32x4 acc2[2];
    acc2[0] = (f32x4){0.f, 0.f, 0.f, 0.f};
    acc2[1] = (f32x4){0.f, 0.f, 0.f, 0.f};

    const int wrow = tid >> 3;          // 0..63
    const int wc0 = (tid & 7) * 8;      // 0..56

    for (int k0 = 0; k0 < 256; k0 += 64) {
        *(bf16x8*)&Ws[wrow * LDR + wc0] =
            *(const bf16x8*)&Wt2[wrow * 256 + k0 + wc0];
        __syncthreads();
#pragma unroll
        for (int ks = 0; ks < 64; ks += 32) {
            const bf16x8 bfrag =
                *(const bf16x8*)&x2s[(nt * 16 + col16) * LDX + k0 + ks + quad * 8];
#pragma unroll
            for (int j = 0; j < 2; ++j) {
                const bf16x8 afrag =
                    *(const bf16x8*)&Ws[((fp * 2 + j) * 16 + col16) * LDR + ks + quad * 8];
                acc2[j] = __builtin_amdgcn_mfma_f32_16x16x32_bf16(afrag, bfrag,
                                                                  acc2[j], 0, 0, 0);
            }
        }
        __syncthreads();
    }

    float elp = 0.f, erp = 0.f;
#pragma unroll
    for (int j = 0; j < 2; ++j) {
        const int ft = fp * 2 + j;
        float alw[4], arw[4];
#pragma unroll
        for (int r = 0; r < 4; ++r) {
            const int d = ft * 16 + quad * 4 + r;
            alw[r] = AL2[d];
            arw[r] = AR2[d];
        }
        const int node = node0 + nt * 16 + col16;
        if (node < n) {
            ushort4 pk;
            pk.x = __half_as_ushort(__float2half(acc2[j][0]));
            pk.y = __half_as_ushort(__float2half(acc2[j][1]));
            pk.z = __half_as_ushort(__float2half(acc2[j][2]));
            pk.w = __half_as_ushort(__float2half(acc2[j][3]));
            *(ushort4*)&Hout[(long long)node * 64 + ft * 16 + quad * 4] = pk;
        }
#pragma unroll
        for (int r = 0; r < 4; ++r) {
            elp = fmaf(acc2[j][r], alw[r], elp);
            erp = fmaf(acc2[j][r], arw[r], erp);
        }
    }
    elp += __shfl_xor(elp, 16, 64);
    elp += __shfl_xor(elp, 32, 64);
    erp += __shfl_xor(erp, 16, 64);
    erp += __shfl_xor(erp, 32, 64);
    if (quad == 0) {
        elq[fp][nt * 16 + col16] = elp;
        erq[fp][nt * 16 + col16] = erp;
    }
    __syncthreads();
    if (fp == 0 && quad == 0) {
        const int ln = nt * 16 + col16;
        const int node = node0 + ln;
        if (node < n) {
            el2[node] = elq[0][ln] + elq[1][ln];
            er2[node] = erq[0][ln] + erq[1][ln];
        }
    }
}

// Layer 2 aggregation: H=1, D=64 fp16. 8 lanes per edge (lane covers 8 feats).
__global__ __launch_bounds__(256) void aggr2_kernel(const unsigned short* __restrict__ Hf,
                                                    const float* __restrict__ el,
                                                    const float* __restrict__ er,
                                                    const int* __restrict__ offs,
                                                    const int* __restrict__ csr,
                                                    const float* __restrict__ bias,
                                                    float* __restrict__ out, int n) {
    const int node = (blockIdx.x * blockDim.x + threadIdx.x) >> 6;
    if (node >= n) return;
    const int lane = threadIdx.x & 63;
    const int g = lane >> 3;       // edge subgroup 0..7
    const int r = lane & 7;        // feats r*8 .. r*8+7
    const int beg = offs[node], end = offs[node + 1];
    const float erv = er[node];

    float acc[8];
#pragma unroll
    for (int q = 0; q < 8; ++q) acc[q] = 0.f;
    float l = 0.f;

    const int nb = (end - beg + 7) >> 3;
    int ci = beg + g; if (ci >= end) ci = end - 1;
    int s = csr[ci];
#pragma unroll 2
    for (int it = 0; it < nb; ++it) {
        const int ei = beg + it * 8 + g;
        const bool ok = ei < end;
        int nci = ei + 8; if (nci >= end) nci = end - 1;
        const int sn = csr[nci];
        float e = el[s] + erv;
        e = (e > 0.f) ? e : SLOPE * e;
        float p = __expf(fminf(e, 80.f));
        if (!ok) p = 0.f;
        const uint4 u = *(const uint4*)(Hf + (s << 6) + (r << 3));   // 16B fp16 x8
        l += p;
        const unsigned uu[4] = {u.x, u.y, u.z, u.w};
#pragma unroll
        for (int q = 0; q < 4; ++q) {
            const float hlo = __half2float(__ushort_as_half((unsigned short)(uu[q] & 0xFFFFu)));
            const float hhi = __half2float(__ushort_as_half((unsigned short)(uu[q] >> 16)));
            acc[2 * q]     = fmaf(p, hlo, acc[2 * q]);
            acc[2 * q + 1] = fmaf(p, hhi, acc[2 * q + 1]);
        }
        s = sn;
    }

#pragma unroll
    for (int q = 0; q < 8; ++q) {
        acc[q] += __shfl_xor(acc[q], 8, 64);
        acc[q] += __shfl_xor(acc[q], 16, 64);
        acc[q] += __shfl_xor(acc[q], 32, 64);
    }
    l += __shfl_xor(l, 8, 64);
    l += __shfl_xor(l, 16, 64);
    l += __shfl_xor(l, 32, 64);

    if (g == 0) {
        const float inv = (l > 0.f) ? 1.f / l : 0.f;
        const float4 b0 = *(const float4*)(bias + r * 8);
        const float4 b1 = *(const float4*)(bias + r * 8 + 4);
        float* op = out + (node << 6) + (r << 3);
        *(float4*)op = make_float4(fmaf(acc[0], inv, b0.x), fmaf(acc[1], inv, b0.y),
                                   fmaf(acc[2], inv, b0.z), fmaf(acc[3], inv, b0.w));
        *(float4*)(op + 4) = make_float4(fmaf(acc[4], inv, b1.x), fmaf(acc[5], inv, b1.y),
                                         fmaf(acc[6], inv, b1.z), fmaf(acc[7], inv, b1.w));
    }
}

// ---------------- launch ----------------

extern "C" void kernel_launch(void* const* d_in, const int* in_sizes, int n_in,
                              void* d_out, int out_size, void* d_ws, size_t ws_size,
                              hipStream_t stream) {
    const float* feat = (const float*)d_in[0];
    const int*   src  = (const int*)d_in[1];
    const int*   dst  = (const int*)d_in[2];
    const float* W1   = (const float*)d_in[3];
    const float* al1  = (const float*)d_in[4];
    const float* ar1  = (const float*)d_in[5];
    const float* b1   = (const float*)d_in[6];
    const float* W2   = (const float*)d_in[7];
    const float* al2  = (const float*)d_in[8];
    const float* ar2  = (const float*)d_in[9];
    const float* b2   = (const float*)d_in[10];
    float* out = (float*)d_out;

    const int IN = 256, HID = 64, OUT = 64, H1 = 4, H2 = 1;
    const int N = in_sizes[0] / IN;   // 50000
    const int E = in_sizes[1];        // 800000

    size_t off = 0;
    auto alloc = [&](size_t bytes) {
        void* p = (char*)d_ws + off;
        off += (bytes + 255) & ~(size_t)255;
        return p;
    };
    int*   deg    = (int*)alloc((size_t)N * 4);
    int*   offs   = (int*)alloc((size_t)(N + 1) * 4);
    int*   bsum   = (int*)alloc((size_t)256 * 4);
    int*   rank   = (int*)alloc((size_t)E * 4);
    int*   csr    = (int*)alloc((size_t)E * 4);
    unsigned short* h1   = (unsigned short*)alloc((size_t)N * H1 * HID * 2); // bf16
    unsigned short* wt1  = (unsigned short*)alloc((size_t)IN * H1 * HID * 2);// bf16 W1^T
    unsigned short* wt2  = (unsigned short*)alloc((size_t)H1 * HID * H2 * OUT * 2); // W2^T
    unsigned short* h2   = (unsigned short*)alloc((size_t)N * H2 * OUT * 2); // fp16
    float* el1    = (float*)alloc((size_t)N * H1 * 4);
    float* er1    = (float*)alloc((size_t)N * H1 * 4);
    float* el2    = (float*)alloc((size_t)N * H2 * 4);
    float* er2    = (float*)alloc((size_t)N * H2 * 4);
    (void)ws_size;

    hipMemsetAsync(deg, 0, (size_t)N * 4, stream);

    const int nb = (N + 255) / 256;   // 196 <= 256 (required by scan2_kernel)
    const int eb = (E + 255) / 256;   // 3125
    const int GB = (N + 127) / 128;   // 391 gemm1 blocks

    // deg+rank || cvt_w in one dispatch
    deg_cvtw_kernel<<<256 + eb, 256, 0, stream>>>(dst, deg, rank, E, W1, W2, wt1, wt2);
    psum_kernel<<<nb, 256, 0, stream>>>(deg, bsum, N);
    scan2_kernel<<<nb, 256, 0, stream>>>(deg, bsum, offs, N);

    // gemm1 (blocks 0..GB-1) || fill (blocks GB..GB+eb-1) in one dispatch
    gemm1_fill<<<GB + eb, 256, 0, stream>>>(feat, wt1, al1, ar1, h1, el1, er1, N, GB,
                                            src, dst, offs, rank, csr, E);

    // aggr1 + gemm2 fused (x2 lives in LDS only)
    aggr1_gemm2<<<(N + 63) / 64, 512, 0, stream>>>(h1, el1, er1, offs, csr, b1,
                                                   wt2, al2, ar2, h2, el2, er2, N);

    aggr2_kernel<<<(N + 3) / 4, 256, 0, stream>>>(h2, el2, er2, offs, csr, b2, out, N);
}

// Round 13
// 280.836 us; speedup vs baseline: 1.1013x; 1.1013x over previous
//
#include <hip/hip_runtime.h>
#include <hip/hip_bf16.h>
#include <hip/hip_fp16.h>
#include <math.h>

#define SLOPE 0.2f

typedef __attribute__((ext_vector_type(8))) short bf16x8;
typedef __attribute__((ext_vector_type(4))) float f32x4;

// bf16 helpers (manual, RNE)
__device__ inline unsigned short f2bf(float f) {
    unsigned u = __float_as_uint(f);
    u += 0x7FFF + ((u >> 16) & 1);
    return (unsigned short)(u >> 16);
}
__device__ inline float bf2f(unsigned short s) {
    return __uint_as_float(((unsigned)s) << 16);
}
// HW packed f32x2 -> bf16x2 (RNE), gfx950. lo = bf16(a), hi = bf16(b).
__device__ inline unsigned cvt_pk_bf16(float a, float b) {
    unsigned r;
    asm("v_cvt_pk_bf16_f32 %0, %1, %2" : "=v"(r) : "v"(a), "v"(b));
    return r;
}

// ---------------- CSR build (separate dispatches; R6: coop grid.sync ~100us
// per barrier on MI355X -> NEVER use cooperative launch for this) ----------
// R12: fusing aggr1+gemm2 (43KB LDS, 512thr) cut occupancy 65->40% and cost
// +31us -- latency-bound gather phases must keep their own resource envelope.

// Fused: cvt_w (blocks 0..255) || deg+rank (remaining blocks).
__global__ void deg_cvtw_kernel(const int* __restrict__ dst, int* __restrict__ deg,
                                int* __restrict__ rank, int E,
                                const float* __restrict__ W1,
                                const float* __restrict__ W2,
                                unsigned short* __restrict__ Wt1,
                                unsigned short* __restrict__ Wt2) {
    if (blockIdx.x < 256) {
        const int k = blockIdx.x, c = threadIdx.x;
        Wt1[c * 256 + k] = f2bf(W1[k * 256 + c]);
        if (c < 64) Wt2[c * 256 + k] = f2bf(W2[k * 64 + c]);
    } else {
        const int i = (blockIdx.x - 256) * blockDim.x + threadIdx.x;
        if (i < E) rank[i] = atomicAdd(&deg[dst[i]], 1);
    }
}

// Two-level device-wide exclusive scan (N <= 65536 so nb <= 256).
__global__ __launch_bounds__(256) void psum_kernel(const int* __restrict__ deg,
                                                   int* __restrict__ bsum, int n) {
    const int t = threadIdx.x;
    const int i = blockIdx.x * 256 + t;
    int v = (i < n) ? deg[i] : 0;
#pragma unroll
    for (int o = 1; o < 64; o <<= 1) v += __shfl_xor(v, o, 64);
    __shared__ int ws[4];
    if ((t & 63) == 0) ws[t >> 6] = v;
    __syncthreads();
    if (t == 0) bsum[blockIdx.x] = ws[0] + ws[1] + ws[2] + ws[3];
}

__global__ __launch_bounds__(256) void scan2_kernel(const int* __restrict__ deg,
                                                    const int* __restrict__ bsum,
                                                    int* __restrict__ offs, int n) {
    const int b = blockIdx.x, t = threadIdx.x;
    const int lane = t & 63, w = t >> 6;

    int contrib = (t < b) ? bsum[t] : 0;
#pragma unroll
    for (int o = 1; o < 64; o <<= 1) contrib += __shfl_xor(contrib, o, 64);
    __shared__ int wsum[4];
    if (lane == 0) wsum[w] = contrib;
    __syncthreads();
    const int base = wsum[0] + wsum[1] + wsum[2] + wsum[3];

    const int i = b * 256 + t;
    const int v = (i < n) ? deg[i] : 0;
    int incl = v;
#pragma unroll
    for (int o = 1; o < 64; o <<= 1) {
        const int u = __shfl_up(incl, o, 64);
        if (lane >= o) incl += u;
    }
    __shared__ int wtot[4];
    if (lane == 63) wtot[w] = incl;
    __syncthreads();
    int wbase = 0;
#pragma unroll
    for (int k = 0; k < 4; ++k)
        if (k < w) wbase += wtot[k];

    const int excl = base + wbase + incl - v;
    if (i < n) offs[i] = excl;
    if (i == n - 1) offs[n] = excl + v;
}

// ---------------- fused fill || layer-1 GEMM -------------------------------
__global__ __launch_bounds__(256) void gemm1_fill(const float* __restrict__ Xf,
                                                  const unsigned short* __restrict__ Wt,
                                                  const float* __restrict__ AL,
                                                  const float* __restrict__ AR,
                                                  unsigned short* __restrict__ Hout,
                                                  float* __restrict__ el,
                                                  float* __restrict__ er, int n, int GB,
                                                  const int* __restrict__ src,
                                                  const int* __restrict__ dst,
                                                  const int* __restrict__ offs,
                                                  const int* __restrict__ rank,
                                                  int* __restrict__ csr_src, int E) {
    constexpr int LDR = 72;
    __shared__ __align__(16) unsigned short Xs[128 * LDR];
    __shared__ __align__(16) unsigned short Ws[256 * LDR];

    if (blockIdx.x >= GB) {
        // ---- fill branch ----
        const int i = (blockIdx.x - GB) * blockDim.x + threadIdx.x;
        if (i < E) csr_src[offs[dst[i]] + rank[i]] = src[i];
        return;
    }

    // ---- gemm1 branch: 128 nodes x ALL 256 outputs, X fetched+cvt ONCE ----
    const int tid = threadIdx.x;
    const int wave = tid >> 6, lane = tid & 63;
    const int col16 = lane & 15, quad = lane >> 4;
    const int node0 = blockIdx.x * 128;

    f32x4 acc[16][2];
#pragma unroll
    for (int ft = 0; ft < 16; ++ft)
#pragma unroll
        for (int nt = 0; nt < 2; ++nt) acc[ft][nt] = (f32x4){0.f, 0.f, 0.f, 0.f};

    const int rr = tid >> 3;
    const int cc = (tid & 7) * 8;

    for (int k0 = 0; k0 < 256; k0 += 64) {
#pragma unroll
        for (int p = 0; p < 4; ++p) {
            const int row = rr + p * 32;
            int gx = node0 + row; if (gx >= n) gx = n - 1;
            const float4* xp = (const float4*)&Xf[(long long)gx * 256 + k0 + cc];
            const float4 a = xp[0];
            const float4 b = xp[1];
            uint4 pk;
            pk.x = cvt_pk_bf16(a.x, a.y);
            pk.y = cvt_pk_bf16(a.z, a.w);
            pk.z = cvt_pk_bf16(b.x, b.y);
            pk.w = cvt_pk_bf16(b.z, b.w);
            *(uint4*)&Xs[row * LDR + cc] = pk;
        }
#pragma unroll
        for (int p = 0; p < 8; ++p) {
            const int row = rr + p * 32;   // 0..255 output features
            *(bf16x8*)&Ws[row * LDR + cc] =
                *(const bf16x8*)&Wt[(long long)row * 256 + k0 + cc];
        }
        __syncthreads();
#pragma unroll
        for (int ks = 0; ks < 64; ks += 32) {
            bf16x8 bfrag[2];
#pragma unroll
            for (int nt = 0; nt < 2; ++nt)
                bfrag[nt] = *(const bf16x8*)&Xs[(wave * 32 + nt * 16 + col16) * LDR +
                                                ks + quad * 8];
#pragma unroll
            for (int ft = 0; ft < 16; ++ft) {
                const bf16x8 afrag =
                    *(const bf16x8*)&Ws[(ft * 16 + col16) * LDR + ks + quad * 8];
                acc[ft][0] = __builtin_amdgcn_mfma_f32_16x16x32_bf16(afrag, bfrag[0],
                                                                     acc[ft][0], 0, 0, 0);
                acc[ft][1] = __builtin_amdgcn_mfma_f32_16x16x32_bf16(afrag, bfrag[1],
                                                                     acc[ft][1], 0, 0, 0);
            }
        }
        __syncthreads();
    }

    float elp[2][4] = {{0.f}, {0.f}};
    float erp[2][4] = {{0.f}, {0.f}};
#pragma unroll
    for (int ft = 0; ft < 16; ++ft) {
        const int hb = ft >> 2;             // head 0..3
        float alw[4], arw[4];
#pragma unroll
        for (int r = 0; r < 4; ++r) {
            const int d = (ft & 3) * 16 + quad * 4 + r;
            alw[r] = AL[hb * 64 + d];
            arw[r] = AR[hb * 64 + d];
        }
#pragma unroll
        for (int nt = 0; nt < 2; ++nt) {
            const int node = node0 + wave * 32 + nt * 16 + col16;
            if (node < n) {
                uint2 pk;
                pk.x = cvt_pk_bf16(acc[ft][nt][0], acc[ft][nt][1]);
                pk.y = cvt_pk_bf16(acc[ft][nt][2], acc[ft][nt][3]);
                *(uint2*)&Hout[(long long)node * 256 + ft * 16 + quad * 4] = pk;
            }
#pragma unroll
            for (int r = 0; r < 4; ++r) {
                elp[nt][hb] = fmaf(acc[ft][nt][r], alw[r], elp[nt][hb]);
                erp[nt][hb] = fmaf(acc[ft][nt][r], arw[r], erp[nt][hb]);
            }
        }
    }
#pragma unroll
    for (int nt = 0; nt < 2; ++nt)
#pragma unroll
        for (int hb = 0; hb < 4; ++hb) {
            elp[nt][hb] += __shfl_xor(elp[nt][hb], 16, 64);
            elp[nt][hb] += __shfl_xor(elp[nt][hb], 32, 64);
            erp[nt][hb] += __shfl_xor(erp[nt][hb], 16, 64);
            erp[nt][hb] += __shfl_xor(erp[nt][hb], 32, 64);
        }
    if (quad == 0) {
#pragma unroll
        for (int nt = 0; nt < 2; ++nt) {
            const int node = node0 + wave * 32 + nt * 16 + col16;
            if (node < n) {
#pragma unroll
                for (int hb = 0; hb < 4; ++hb) {
                    el[node * 4 + hb] = elp[nt][hb];
                    er[node * 4 + hb] = erp[nt][hb];
                }
            }
        }
    }
}

// ---------------- layer-2 GEMM: LDS-tiled bf16 MFMA (M=64) ----------------
// Output h2 stored as fp16 (halves aggr2's gather bytes; 2^-11 rel err).
__global__ __launch_bounds__(256) void gemm2_mfma(const unsigned short* __restrict__ Xbf,
                                                  const unsigned short* __restrict__ Wt,
                                                  const float* __restrict__ AL,
                                                  const float* __restrict__ AR,
                                                  unsigned short* __restrict__ Hout,
                                                  float* __restrict__ el,
                                                  float* __restrict__ er, int n) {
    constexpr int LDR = 72;
    __shared__ __align__(16) unsigned short Xs[128 * LDR];
    __shared__ __align__(16) unsigned short Ws[64 * LDR];

    const int tid = threadIdx.x;
    const int wave = tid >> 6, lane = tid & 63;
    const int col16 = lane & 15, quad = lane >> 4;
    const int node0 = blockIdx.x * 128;

    f32x4 acc[4][2];
#pragma unroll
    for (int ft = 0; ft < 4; ++ft)
#pragma unroll
        for (int nt = 0; nt < 2; ++nt) acc[ft][nt] = (f32x4){0.f, 0.f, 0.f, 0.f};

    const int rr = tid >> 3;
    const int cc = (tid & 7) * 8;

    for (int k0 = 0; k0 < 256; k0 += 64) {
#pragma unroll
        for (int p = 0; p < 4; ++p) {
            const int row = rr + p * 32;
            int gx = node0 + row; if (gx >= n) gx = n - 1;
            *(bf16x8*)&Xs[row * LDR + cc] =
                *(const bf16x8*)&Xbf[(long long)gx * 256 + k0 + cc];
        }
#pragma unroll
        for (int p = 0; p < 2; ++p) {
            const int row = rr + p * 32;
            *(bf16x8*)&Ws[row * LDR + cc] =
                *(const bf16x8*)&Wt[(long long)row * 256 + k0 + cc];
        }
        __syncthreads();
#pragma unroll
        for (int ks = 0; ks < 64; ks += 32) {
            bf16x8 bfrag[2];
#pragma unroll
            for (int nt = 0; nt < 2; ++nt)
                bfrag[nt] = *(const bf16x8*)&Xs[(wave * 32 + nt * 16 + col16) * LDR +
                                                ks + quad * 8];
#pragma unroll
            for (int ft = 0; ft < 4; ++ft) {
                const bf16x8 afrag =
                    *(const bf16x8*)&Ws[(ft * 16 + col16) * LDR + ks + quad * 8];
                acc[ft][0] = __builtin_amdgcn_mfma_f32_16x16x32_bf16(afrag, bfrag[0],
                                                                     acc[ft][0], 0, 0, 0);
                acc[ft][1] = __builtin_amdgcn_mfma_f32_16x16x32_bf16(afrag, bfrag[1],
                                                                     acc[ft][1], 0, 0, 0);
            }
        }
        __syncthreads();
    }

    float elp[2] = {0.f, 0.f}, erp[2] = {0.f, 0.f};
#pragma unroll
    for (int ft = 0; ft < 4; ++ft) {
        float alw[4], arw[4];
#pragma unroll
        for (int r = 0; r < 4; ++r) {
            const int d = ft * 16 + quad * 4 + r;
            alw[r] = AL[d];
            arw[r] = AR[d];
        }
#pragma unroll
        for (int nt = 0; nt < 2; ++nt) {
            const int node = node0 + wave * 32 + nt * 16 + col16;
            if (node < n) {
                ushort4 pk;
                pk.x = __half_as_ushort(__float2half(acc[ft][nt][0]));
                pk.y = __half_as_ushort(__float2half(acc[ft][nt][1]));
                pk.z = __half_as_ushort(__float2half(acc[ft][nt][2]));
                pk.w = __half_as_ushort(__float2half(acc[ft][nt][3]));
                *(ushort4*)&Hout[(long long)node * 64 + ft * 16 + quad * 4] = pk;
            }
#pragma unroll
            for (int r = 0; r < 4; ++r) {
                elp[nt] = fmaf(acc[ft][nt][r], alw[r], elp[nt]);
                erp[nt] = fmaf(acc[ft][nt][r], arw[r], erp[nt]);
            }
        }
    }
#pragma unroll
    for (int nt = 0; nt < 2; ++nt) {
        elp[nt] += __shfl_xor(elp[nt], 16, 64);
        elp[nt] += __shfl_xor(elp[nt], 32, 64);
        erp[nt] += __shfl_xor(erp[nt], 16, 64);
        erp[nt] += __shfl_xor(erp[nt], 32, 64);
    }
    if (quad == 0) {
#pragma unroll
        for (int nt = 0; nt < 2; ++nt) {
            const int node = node0 + wave * 32 + nt * 16 + col16;
            if (node < n) {
                el[node] = elp[nt];
                er[node] = erp[nt];
            }
        }
    }
}

// ---------------- aggregation, 4 edges per wave-iteration ----------------
// Softmax numerators inline. One-iteration s-prefetch pipeline hides the
// csr->s->gather dependent chain. unroll 2 only (R4: unroll 4 kills occupancy).
__global__ __launch_bounds__(256) void aggr1_kernel(const unsigned short* __restrict__ Hf,
                                                    const float* __restrict__ el,
                                                    const float* __restrict__ er,
                                                    const int* __restrict__ offs,
                                                    const int* __restrict__ csr,
                                                    const float* __restrict__ bias,
                                                    unsigned short* __restrict__ out,
                                                    int n) {
    const int node = (blockIdx.x * blockDim.x + threadIdx.x) >> 6;
    if (node >= n) return;
    const int lane = threadIdx.x & 63;
    const int g = lane >> 4;       // edge subgroup
    const int r = lane & 15;       // feature slot: feats r*16 .. r*16+15
    const int h = r >> 2;          // head of this feature slot
    const int beg = offs[node], end = offs[node + 1];
    const float erv = er[node * 4 + h];

    float acc[16];
#pragma unroll
    for (int q = 0; q < 16; ++q) acc[q] = 0.f;
    float l = 0.f;

    const int nb = (end - beg + 3) >> 2;
    int ci = beg + g; if (ci >= end) ci = end - 1;
    int s = csr[ci];                       // prologue: first edge index
#pragma unroll 2
    for (int it = 0; it < nb; ++it) {
        const int ei = beg + it * 4 + g;
        const bool ok = ei < end;
        int nci = ei + 4; if (nci >= end) nci = end - 1;
        const int sn = csr[nci];           // prefetch next iteration's source
        float e = el[s * 4 + h] + erv;
        e = (e > 0.f) ? e : SLOPE * e;
        float p = __expf(fminf(e, 80.f));
        if (!ok) p = 0.f;
        const uint4* hp = (const uint4*)(Hf + (s << 8) + (r << 4));
        const uint4 u0 = hp[0];
        const uint4 u1 = hp[1];
        l += p;
        const unsigned uu[8] = {u0.x, u0.y, u0.z, u0.w, u1.x, u1.y, u1.z, u1.w};
#pragma unroll
        for (int q = 0; q < 8; ++q) {
            const float flo = __uint_as_float(uu[q] << 16);
            const float fhi = __uint_as_float(uu[q] & 0xFFFF0000u);
            acc[2 * q]     = fmaf(p, flo, acc[2 * q]);
            acc[2 * q + 1] = fmaf(p, fhi, acc[2 * q + 1]);
        }
        s = sn;
    }

#pragma unroll
    for (int q = 0; q < 16; ++q) {
        acc[q] += __shfl_xor(acc[q], 16, 64);
        acc[q] += __shfl_xor(acc[q], 32, 64);
    }
    l += __shfl_xor(l, 16, 64);
    l += __shfl_xor(l, 32, 64);

    if (g == 0) {
        const float inv = (l > 0.f) ? 1.f / l : 0.f;
        unsigned o[8];
#pragma unroll
        for (int q = 0; q < 8; ++q) {
            float v0 = acc[2 * q]     * inv + bias[r * 16 + 2 * q];
            float v1 = acc[2 * q + 1] * inv + bias[r * 16 + 2 * q + 1];
            v0 = (v0 > 0.f) ? v0 : expm1f(v0);   // ELU
            v1 = (v1 > 0.f) ? v1 : expm1f(v1);
            o[q] = cvt_pk_bf16(v0, v1);
        }
        uint4* op = (uint4*)(out + (node << 8) + (r << 4));
        op[0] = make_uint4(o[0], o[1], o[2], o[3]);
        op[1] = make_uint4(o[4], o[5], o[6], o[7]);
    }
}

// Layer 2: H=1, D=64 fp16. 8 lanes per edge (lane covers 8 feats, 1 uint4)
// -> 8 edges per wave-iteration: half the serial steps of the 16-lane form.
__global__ __launch_bounds__(256) void aggr2_kernel(const unsigned short* __restrict__ Hf,
                                                    const float* __restrict__ el,
                                                    const float* __restrict__ er,
                                                    const int* __restrict__ offs,
                                                    const int* __restrict__ csr,
                                                    const float* __restrict__ bias,
                                                    float* __restrict__ out, int n) {
    const int node = (blockIdx.x * blockDim.x + threadIdx.x) >> 6;
    if (node >= n) return;
    const int lane = threadIdx.x & 63;
    const int g = lane >> 3;       // edge subgroup 0..7
    const int r = lane & 7;        // feats r*8 .. r*8+7
    const int beg = offs[node], end = offs[node + 1];
    const float erv = er[node];

    float acc[8];
#pragma unroll
    for (int q = 0; q < 8; ++q) acc[q] = 0.f;
    float l = 0.f;

    const int nb = (end - beg + 7) >> 3;
    int ci = beg + g; if (ci >= end) ci = end - 1;
    int s = csr[ci];
#pragma unroll 2
    for (int it = 0; it < nb; ++it) {
        const int ei = beg + it * 8 + g;
        const bool ok = ei < end;
        int nci = ei + 8; if (nci >= end) nci = end - 1;
        const int sn = csr[nci];
        float e = el[s] + erv;
        e = (e > 0.f) ? e : SLOPE * e;
        float p = __expf(fminf(e, 80.f));
        if (!ok) p = 0.f;
        const uint4 u = *(const uint4*)(Hf + (s << 6) + (r << 3));   // 16B fp16 x8
        l += p;
        const unsigned uu[4] = {u.x, u.y, u.z, u.w};
#pragma unroll
        for (int q = 0; q < 4; ++q) {
            const float hlo = __half2float(__ushort_as_half((unsigned short)(uu[q] & 0xFFFFu)));
            const float hhi = __half2float(__ushort_as_half((unsigned short)(uu[q] >> 16)));
            acc[2 * q]     = fmaf(p, hlo, acc[2 * q]);
            acc[2 * q + 1] = fmaf(p, hhi, acc[2 * q + 1]);
        }
        s = sn;
    }

#pragma unroll
    for (int q = 0; q < 8; ++q) {
        acc[q] += __shfl_xor(acc[q], 8, 64);
        acc[q] += __shfl_xor(acc[q], 16, 64);
        acc[q] += __shfl_xor(acc[q], 32, 64);
    }
    l += __shfl_xor(l, 8, 64);
    l += __shfl_xor(l, 16, 64);
    l += __shfl_xor(l, 32, 64);

    if (g == 0) {
        const float inv = (l > 0.f) ? 1.f / l : 0.f;
        const float4 b0 = *(const float4*)(bias + r * 8);
        const float4 b1 = *(const float4*)(bias + r * 8 + 4);
        float* op = out + (node << 6) + (r << 3);
        *(float4*)op = make_float4(fmaf(acc[0], inv, b0.x), fmaf(acc[1], inv, b0.y),
                                   fmaf(acc[2], inv, b0.z), fmaf(acc[3], inv, b0.w));
        *(float4*)(op + 4) = make_float4(fmaf(acc[4], inv, b1.x), fmaf(acc[5], inv, b1.y),
                                         fmaf(acc[6], inv, b1.z), fmaf(acc[7], inv, b1.w));
    }
}

// ---------------- launch ----------------

extern "C" void kernel_launch(void* const* d_in, const int* in_sizes, int n_in,
                              void* d_out, int out_size, void* d_ws, size_t ws_size,
                              hipStream_t stream) {
    const float* feat = (const float*)d_in[0];
    const int*   src  = (const int*)d_in[1];
    const int*   dst  = (const int*)d_in[2];
    const float* W1   = (const float*)d_in[3];
    const float* al1  = (const float*)d_in[4];
    const float* ar1  = (const float*)d_in[5];
    const float* b1   = (const float*)d_in[6];
    const float* W2   = (const float*)d_in[7];
    const float* al2  = (const float*)d_in[8];
    const float* ar2  = (const float*)d_in[9];
    const float* b2   = (const float*)d_in[10];
    float* out = (float*)d_out;

    const int IN = 256, HID = 64, OUT = 64, H1 = 4, H2 = 1;
    const int N = in_sizes[0] / IN;   // 50000
    const int E = in_sizes[1];        // 800000

    size_t off = 0;
    auto alloc = [&](size_t bytes) {
        void* p = (char*)d_ws + off;
        off += (bytes + 255) & ~(size_t)255;
        return p;
    };
    int*   deg    = (int*)alloc((size_t)N * 4);
    int*   offs   = (int*)alloc((size_t)(N + 1) * 4);
    int*   bsum   = (int*)alloc((size_t)256 * 4);
    int*   rank   = (int*)alloc((size_t)E * 4);
    int*   csr    = (int*)alloc((size_t)E * 4);
    unsigned short* h1   = (unsigned short*)alloc((size_t)N * H1 * HID * 2); // bf16
    unsigned short* wt1  = (unsigned short*)alloc((size_t)IN * H1 * HID * 2);// bf16 W1^T
    unsigned short* wt2  = (unsigned short*)alloc((size_t)H1 * HID * H2 * OUT * 2); // W2^T
    unsigned short* x2bf = (unsigned short*)alloc((size_t)N * H1 * HID * 2); // bf16 x2
    unsigned short* h2   = (unsigned short*)alloc((size_t)N * H2 * OUT * 2); // fp16
    float* el1    = (float*)alloc((size_t)N * H1 * 4);
    float* er1    = (float*)alloc((size_t)N * H1 * 4);
    float* el2    = (float*)alloc((size_t)N * H2 * 4);
    float* er2    = (float*)alloc((size_t)N * H2 * 4);
    (void)ws_size;

    hipMemsetAsync(deg, 0, (size_t)N * 4, stream);

    const int nb = (N + 255) / 256;   // 196 <= 256 (required by scan2_kernel)
    const int eb = (E + 255) / 256;   // 3125
    const int GB = (N + 127) / 128;   // 391 gemm1 blocks

    // deg+rank || cvt_w in one dispatch
    deg_cvtw_kernel<<<256 + eb, 256, 0, stream>>>(dst, deg, rank, E, W1, W2, wt1, wt2);
    psum_kernel<<<nb, 256, 0, stream>>>(deg, bsum, N);
    scan2_kernel<<<nb, 256, 0, stream>>>(deg, bsum, offs, N);

    // gemm1 (blocks 0..GB-1) || fill (blocks GB..GB+eb-1) in one dispatch
    gemm1_fill<<<GB + eb, 256, 0, stream>>>(feat, wt1, al1, ar1, h1, el1, er1, N, GB,
                                            src, dst, offs, rank, csr, E);

    aggr1_kernel<<<(N + 3) / 4, 256, 0, stream>>>(h1, el1, er1, offs, csr, b1, x2bf, N);
    // ---- layer 2 ----
    gemm2_mfma<<<(N + 127) / 128, 256, 0, stream>>>(x2bf, wt2, al2, ar2, h2, el2, er2, N);
    aggr2_kernel<<<(N + 3) / 4, 256, 0, stream>>>(h2, el2, er2, offs, csr, b2, out, N);
}